// Round 9
// baseline (220.334 us; speedup 1.0000x reference)
//
#include <hip/hip_runtime.h>

// out[b,h,w,dy*9+dx] = leaky_relu( mean_c( prv[b,h,w,c] * nxt[b,h+dy-4,w+dx-4,c] ), 0.1 )
// R7c: VALU v_dot2_f32_f16 formulation (R7b with prv pixel-stride fix: 192*s, not 768*s).
// Thread owns 4 consecutive w-pixels (acc 4x27). dy split 3-way over blockIdx.z.
// nxt staged in LDS as f16 chunks (8ch=16B); one ds_read_b128 feeds up to 4 px.

#define B_ 8
#define H_ 128
#define W_ 128
#define C_ 192
#define ND 9
#define NDISP 81
#define NDY 3           // dy per block
#define TH 8            // h rows per block (ty)
#define TW 64           // w cols per block
#define PX 4            // pixels per thread along w
#define KC 8            // channels per k-step
#define NK 24           // C_/KC
#define BROWS (TH + NDY - 1)   // 10 nxt rows staged
#define BCOLS (TW + 8)         // 72 nxt cols staged
#define BCH (BROWS * BCOLS)    // 720 16B chunks per k-step
#define NSLOT 6                // ceil(720/128); slot 5 covers tid<80
#define NJ (PX + ND - 1)       // 12 staged cols touched per (dy,kstep)

typedef __fp16 half2_t __attribute__((ext_vector_type(2)));   // native type of cvt_pkrtz/fdot2
typedef unsigned int u32;

#if defined(__has_builtin) && __has_builtin(__builtin_amdgcn_fdot2)
#define FDOT2(a, b, c) __builtin_amdgcn_fdot2((a), (b), (c), false)
#else
#define FDOT2(a, b, c) ((c) + (float)(a)[0] * (float)(b)[0] + (float)(a)[1] * (float)(b)[1])
#endif

// bank-spread swizzle on 16B-chunk column index (consistent on write & read)
static __device__ __forceinline__ int swz(int col) { return col ^ ((col >> 3) & 3); }

static __device__ __forceinline__ u32 pk(float a, float b) {
    half2_t h = __builtin_amdgcn_cvt_pkrtz(a, b);   // v_cvt_pkrtz_f16_f32
    return __builtin_bit_cast(u32, h);
}

__global__ __launch_bounds__(128, 2)
void cv_dot2(const float* __restrict__ prv, const float* __restrict__ nxt,
             float* __restrict__ out) {
    __shared__ uint4 sB[2][BCH];   // 2 x 11.25 KB

    const int tid = threadIdx.x;
    const int tx = tid & 15;       // w-group: pixels w0 + 4*tx + s
    const int ty = tid >> 4;       // row 0..7
    const int w0 = blockIdx.x * TW;
    const int h0 = blockIdx.y * TH;
    const int z  = blockIdx.z;     // b*3 + g
    const int b  = z / 3;
    const int g  = z - 3 * b;
    const int dy0 = 3 * g;

    // ---- B staging slots: element offset into nxt, validity, swizzled LDS slot
    int boffB[NSLOT], sl[NSLOT];
    bool ok[NSLOT];
#pragma unroll
    for (int i = 0; i < NSLOT; ++i) {
        const int idx = tid + i * 128;
        ok[i] = false; boffB[i] = 0; sl[i] = 0;
        if (idx < BCH) {
            const int row = idx / BCOLS;
            const int col = idx - row * BCOLS;
            const int gh = h0 + dy0 - 4 + row;
            const int gw = w0 - 4 + col;
            ok[i] = ((unsigned)gh < (unsigned)H_) && ((unsigned)gw < (unsigned)W_);
            const int ghc = ok[i] ? gh : 0;
            const int gwc = ok[i] ? gw : 0;
            boffB[i] = ((b * H_ + ghc) * W_ + gwc) * C_;
            sl[i] = row * BCOLS + swz(col);
        }
    }

    // ---- prv: one base offset; pixel s at +C_*s, kstep at +co
    const int ppo = ((b * H_ + h0 + ty) * W_ + w0 + 4 * tx) * C_;

    // ---- LDS read column offsets (uint4-element index), swizzled
    int eoff[NJ];
#pragma unroll
    for (int j = 0; j < NJ; ++j) eoff[j] = swz(4 * tx + j);

    float acc[PX][NDY][ND];
#pragma unroll
    for (int s = 0; s < PX; ++s)
#pragma unroll
        for (int jd = 0; jd < NDY; ++jd)
#pragma unroll
            for (int dx = 0; dx < ND; ++dx) acc[s][jd][dx] = 0.f;

    for (int ks = 0; ks < NK; ++ks) {
        const int co = ks * KC;
        uint4* buf = sB[ks & 1];

        // ---- load prv (4 px x 8 ch f32) and B slots; all loads issued before use
        float4 pxx[PX], pyy[PX];
#pragma unroll
        for (int s = 0; s < PX; ++s) {
            const float* p = prv + ppo + C_ * s + co;
            pxx[s] = *(const float4*)p;
            pyy[s] = *(const float4*)(p + 4);
        }
        float4 bxx[NSLOT], byy[NSLOT];
#pragma unroll
        for (int i = 0; i < NSLOT; ++i) {
            bxx[i] = make_float4(0.f, 0.f, 0.f, 0.f);
            byy[i] = bxx[i];
            if (ok[i]) {
                const float* p = nxt + boffB[i] + co;
                bxx[i] = *(const float4*)p;
                byy[i] = *(const float4*)(p + 4);
            }
        }

        // ---- convert prv to half2 words
        u32 paw[PX][4];
#pragma unroll
        for (int s = 0; s < PX; ++s) {
            paw[s][0] = pk(pxx[s].x, pxx[s].y);
            paw[s][1] = pk(pxx[s].z, pxx[s].w);
            paw[s][2] = pk(pyy[s].x, pyy[s].y);
            paw[s][3] = pk(pyy[s].z, pyy[s].w);
        }

        // ---- write B chunks to LDS (f16), swizzled slots
#pragma unroll
        for (int i = 0; i < NSLOT; ++i) {
            if (i < NSLOT - 1 || tid < BCH - (NSLOT - 1) * 128) {
                buf[sl[i]] = make_uint4(pk(bxx[i].x, bxx[i].y), pk(bxx[i].z, bxx[i].w),
                                        pk(byy[i].x, byy[i].y), pk(byy[i].z, byy[i].w));
            }
        }
        __syncthreads();

        // ---- compute: 3 dy x 12 cols; each b128 chunk feeds up to 4 px x 4 dot2
#pragma unroll
        for (int jd = 0; jd < NDY; ++jd) {
            const uint4* rowp = buf + (ty + jd) * BCOLS;
#pragma unroll
            for (int j = 0; j < NJ; ++j) {
                const uint4 ch = rowp[eoff[j]];
                const half2_t c0 = __builtin_bit_cast(half2_t, ch.x);
                const half2_t c1 = __builtin_bit_cast(half2_t, ch.y);
                const half2_t c2 = __builtin_bit_cast(half2_t, ch.z);
                const half2_t c3 = __builtin_bit_cast(half2_t, ch.w);
#pragma unroll
                for (int s = 0; s < PX; ++s) {
                    const int dx = j - s;          // compile-time after unroll
                    if (dx >= 0 && dx < ND) {
                        float a = acc[s][jd][dx];
                        a = FDOT2(__builtin_bit_cast(half2_t, paw[s][0]), c0, a);
                        a = FDOT2(__builtin_bit_cast(half2_t, paw[s][1]), c1, a);
                        a = FDOT2(__builtin_bit_cast(half2_t, paw[s][2]), c2, a);
                        a = FDOT2(__builtin_bit_cast(half2_t, paw[s][3]), c3, a);
                        acc[s][jd][dx] = a;
                    }
                }
            }
        }
        // no trailing barrier: next iteration writes the OTHER buffer; any wave still
        // computing holds the current buffer, and all waves passed this iter's barrier.
    }

    // ---- epilogue: mean + leaky relu; thread owns (h0+ty, w0+4tx+s), dy block dy0..dy0+2
    const float inv = 1.0f / (float)C_;
#pragma unroll
    for (int s = 0; s < PX; ++s) {
        float* o = out + (size_t)((b * H_ + h0 + ty) * W_ + w0 + 4 * tx + s) * NDISP + dy0 * ND;
#pragma unroll
        for (int jd = 0; jd < NDY; ++jd)
#pragma unroll
            for (int dx = 0; dx < ND; ++dx) {
                const float v = acc[s][jd][dx] * inv;
                o[jd * ND + dx] = v >= 0.f ? v : 0.1f * v;
            }
    }
}

extern "C" void kernel_launch(void* const* d_in, const int* in_sizes, int n_in,
                              void* d_out, int out_size, void* d_ws, size_t ws_size,
                              hipStream_t stream) {
    const float* prv = (const float*)d_in[0];
    const float* nxt = (const float*)d_in[1];
    float* out = (float*)d_out;

    dim3 grid(W_ / TW, H_ / TH, B_ * 3);   // (2, 16, 24) = 768 blocks x 128 threads
    cv_dot2<<<grid, 128, 0, stream>>>(prv, nxt, out);
}

// Round 10
// 81.825 us; speedup vs baseline: 2.6928x; 2.6928x over previous
//
#include <hip/hip_runtime.h>
#include <hip/hip_bf16.h>

// out[b,h,w,dy*9+dx] = leaky_relu( mean_c( prv[b,h,w,c] * nxt[b,h+dy-4,w+dx-4,c] ), 0.1 )
// R10: R5's banded MFMA structure + COALESCED staging.
//  - KS=64 channels per k-step (NK=3): each pixel contributes a contiguous 256B f32 run.
//  - staging granule = 4 channels = one 16B dwordx4 per lane, [pixel][c16] order:
//    a wave's 64 lanes = 4 pixels x 16 granules, contiguous -> 16 cache lines per
//    wave-load (ideal), vs 64 lines in R1-R7 (768B pixel stride) -- the measured
//    line-request-path bottleneck.
//  - LDS: granule-transposed slot = c16*STRIDE + p with ODD stride (65/289):
//    ds_write_b64 banks spread (stride odd), frag reads = 2x ds_read_b64, lanes
//    at 8B stride (conflict-free).

#define B_ 8
#define H_ 128
#define W_ 128
#define C_ 192
#define ND 9
#define NDISP 81
#define HT 4            // output rows per block (one per wave)
#define WT 16           // output cols per block
#define KS 64           // channels per k-step
#define NK 3            // 192/64
#define BROWS 12        // HT + ND - 1 nxt rows staged
#define BCOLS 24        // WT + 8 nxt cols staged
#define APIX (HT * WT)         // 64 prv pixels
#define BPIX (BROWS * BCOLS)   // 288 nxt pixels
#define ASTR 65                // odd granule stride (c16-major) for A
#define BSTR 289               // odd granule stride for B
#define AGRN (16 * ASTR)       // 1040 granules
#define BGRN (16 * BSTR)       // 4624 granules
#define NSA 4                  // A slots per thread (64*16/256)
#define NSB 18                 // B slots per thread (288*16/256)

typedef short short8 __attribute__((ext_vector_type(8)));
typedef short short4_t __attribute__((ext_vector_type(4)));
typedef float f32x4 __attribute__((ext_vector_type(4)));

static __device__ __forceinline__ short bf1(float f) {
    __hip_bfloat16 h = __float2bfloat16(f);   // pairs fuse to v_cvt_pk_bf16_f32
    return __builtin_bit_cast(short, h);
}

static __device__ __forceinline__ short4_t cvt4(float4 v) {
    short4_t r;
    r[0] = bf1(v.x); r[1] = bf1(v.y); r[2] = bf1(v.z); r[3] = bf1(v.w);
    return r;
}

static __device__ __forceinline__ short8 cat(short4_t u, short4_t v) {
    return __builtin_shufflevector(u, v, 0, 1, 2, 3, 4, 5, 6, 7);
}

__global__ __launch_bounds__(256, 3)
void cv_mfma(const float* __restrict__ prv, const float* __restrict__ nxt,
             float* __restrict__ out) {
    __shared__ short4_t sm[AGRN + BGRN];   // 45.3 KB -> 3 blocks/CU
    short4_t* sA = sm;
    short4_t* sB = sm + AGRN;

    const int tid = threadIdx.x;
    const int w0 = blockIdx.x * WT;
    const int h0 = blockIdx.y * HT;
    const int b  = blockIdx.z;

    const int lane = tid & 63;
    const int wid  = tid >> 6;      // 0..3: wave handles output row h0+wid
    const int lq = lane & 15;
    const int lc = lane >> 4;

    const int tp  = tid >> 4;       // 0..15: pixel sub-index for staging
    const int c16 = tid & 15;       // 0..15: 4-channel granule index

    // ---- hoisted global element-offsets (32-bit; k-step adds ks*KS)
    int aoff[NSA];
#pragma unroll
    for (int i = 0; i < NSA; ++i) {
        const int p = tp + 16 * i;        // 0..63
        const int r = p >> 4;
        const int pc = p & 15;
        aoff[i] = ((b * H_ + h0 + r) * W_ + w0 + pc) * C_ + c16 * 4;
    }
    int boff[NSB];
    unsigned bmask = 0;
#pragma unroll
    for (int i = 0; i < NSB; ++i) {
        const int p = tp + 16 * i;        // 0..287
        const int row = p / BCOLS;
        const int col = p - row * BCOLS;
        const int gh = h0 - 4 + row;
        const int gw = w0 - 4 + col;
        const bool ok = ((unsigned)gh < (unsigned)H_) && ((unsigned)gw < (unsigned)W_);
        if (ok) bmask |= (1u << i);
        boff[i] = ((b * H_ + (ok ? gh : 0)) * W_ + (ok ? gw : 0)) * C_ + c16 * 4;
    }

    f32x4 acc[ND][2];
#pragma unroll
    for (int d = 0; d < ND; ++d) {
        acc[d][0] = (f32x4){0.f, 0.f, 0.f, 0.f};
        acc[d][1] = (f32x4){0.f, 0.f, 0.f, 0.f};
    }

    for (int ks = 0; ks < NK; ++ks) {
        if (ks) __syncthreads();
        const int co = ks * KS;

        // ---- stage A: 4 coalesced dwordx4 per thread
        {
            float4 v[NSA];
#pragma unroll
            for (int i = 0; i < NSA; ++i)
                v[i] = *(const float4*)(prv + aoff[i] + co);
#pragma unroll
            for (int i = 0; i < NSA; ++i)
                sA[c16 * ASTR + tp + 16 * i] = cvt4(v[i]);
        }
        // ---- stage B: 18 slots in 3 batches of 6 (bounded reg pressure, batched ILP)
#pragma unroll
        for (int bt = 0; bt < 3; ++bt) {
            float4 v[6];
#pragma unroll
            for (int j = 0; j < 6; ++j) {
                const int i = 6 * bt + j;
                v[j] = make_float4(0.f, 0.f, 0.f, 0.f);
                if (bmask & (1u << i))
                    v[j] = *(const float4*)(nxt + boff[i] + co);
            }
#pragma unroll
            for (int j = 0; j < 6; ++j) {
                const int i = 6 * bt + j;
                sB[c16 * BSTR + tp + 16 * i] = cvt4(v[j]);
            }
        }
        __syncthreads();

        // ---- A frags: k-sub s covers channels co + 32s + 8*lc .. +7
        short8 a[2];
#pragma unroll
        for (int s = 0; s < 2; ++s) {
            const int cg = 8 * s + 2 * lc;
            const int pA = wid * WT + lq;
            a[s] = cat(sA[cg * ASTR + pA], sA[(cg + 1) * ASTR + pA]);
        }
        // ---- compute: 9 dy x 2 k-subs x 2 col-tiles
#pragma unroll
        for (int dy = 0; dy < ND; ++dy) {
            const int pp0 = (wid + dy) * BCOLS + lq;
#pragma unroll
            for (int s = 0; s < 2; ++s) {
                const int cg = 8 * s + 2 * lc;
                const short8 b0 = cat(sB[cg * BSTR + pp0],     sB[(cg + 1) * BSTR + pp0]);
                const short8 b1 = cat(sB[cg * BSTR + pp0 + 8], sB[(cg + 1) * BSTR + pp0 + 8]);
                acc[dy][0] = __builtin_amdgcn_mfma_f32_16x16x32_bf16(a[s], b0, acc[dy][0], 0, 0, 0);
                acc[dy][1] = __builtin_amdgcn_mfma_f32_16x16x32_bf16(a[s], b1, acc[dy][1], 0, 0, 0);
            }
        }
    }

    // ---- epilogue (identical to R5, verified): D layout col=lane&15, row=4*(lane>>4)+reg.
    // rows r<8 valid in tile0 (dx=q-r), rows r>=8 in tile1 (dx=q-r+8).
    const float inv = 1.0f / (float)C_;
    const int h = h0 + wid;
    if (lc < 2) {
#pragma unroll
        for (int rg = 0; rg < 4; ++rg) {
            const int r = 4 * lc + rg;
            const int dx = lq - r;
            if (dx >= 0 && dx <= 8) {
                float* o = out + (size_t)((b * H_ + h) * W_ + w0 + r) * NDISP + dx;
#pragma unroll
                for (int dy = 0; dy < ND; ++dy) {
                    const float v = acc[dy][0][rg] * inv;
                    o[dy * ND] = v >= 0.f ? v : 0.1f * v;
                }
            }
        }
    } else {
#pragma unroll
        for (int rg = 0; rg < 4; ++rg) {
            const int r = 4 * lc + rg;
            const int dx = lq - r + 8;
            if (dx >= 0 && dx <= 8) {
                float* o = out + (size_t)((b * H_ + h) * W_ + w0 + r) * NDISP + dx;
#pragma unroll
                for (int dy = 0; dy < ND; ++dy) {
                    const float v = acc[dy][1][rg] * inv;
                    o[dy * ND] = v >= 0.f ? v : 0.1f * v;
                }
            }
        }
    }
}

extern "C" void kernel_launch(void* const* d_in, const int* in_sizes, int n_in,
                              void* d_out, int out_size, void* d_ws, size_t ws_size,
                              hipStream_t stream) {
    const float* prv = (const float*)d_in[0];
    const float* nxt = (const float*)d_in[1];
    float* out = (float*)d_out;

    dim3 grid(W_ / WT, H_ / HT, B_);   // (8, 32, 8) = 2048 blocks
    cv_mfma<<<grid, 256, 0, stream>>>(prv, nxt, out);
}